// Round 10
// baseline (110.395 us; speedup 1.0000x reference)
//
#include <hip/hip_runtime.h>
#include <math.h>

// NMSLoss4: B=8, N=2048, G=64. Key-sorted (desc) space: every killer of e has
// index < e, so ONE ordered Gauss-Seidel sweep gives the exact sequential-NMS
// fixed point. Round 9: suppression graph stored as an exact triangular
// adjacency BITMASK (adj[e] = u64 words 0..e>>6; bit i => IoU(i,e)>0.5).
// Sweep keeps sel[] in registers (fully unrolled), no LDS/caps/overflow in
// the critical path. Rank-partial sort (512 blocks) from round 8 retained.

#define B_IMG 8
#define NN 2048
#define GG 64
#define MIN_H 50.0f
#define EPSF 1e-6f
#define TILE 256
#define NTILE 8
#define NPAIRT 36            // triangular 256x256 tile pairs
#define CSLICE 64
#define ADJ_U64 33792        // sum over words W: 64*(W+1), W=0..31

// per-image ws layout (bytes)
#define OFF_SBOX  0          // float4[2048]                 32768
#define OFF_GTPI  32768      // f32[2048]                     8192
#define OFF_PULL  40960      // f32[2048]                     8192
#define OFF_AGTI  49152      // s8[2048]                      2048
#define OFF_NPOSP 51200      // u32[8] per-chunk counts (+pad)
#define OFF_RANKP 51456      // u16[8][2048]                 32768
#define OFF_ADJ   84224      // u64[33792] triangular       270336
#define IMG_STRIDE 354560

__device__ __forceinline__ float iou_pair(
    float ax1, float ay1, float ax2, float ay2,
    float bx1, float by1, float bx2, float by2) {
  float area_a = (ax2 - ax1) * (ay2 - ay1);
  float area_b = (bx2 - bx1) * (by2 - by1);
  float lx = fmaxf(ax1, bx1), ly = fmaxf(ay1, by1);
  float rx = fminf(ax2, bx2), ry = fminf(ay2, by2);
  float w = fmaxf(rx - lx, 0.0f), h = fmaxf(ry - ly, 0.0f);
  float inter = w * h;
  return inter / (area_a + area_b - inter + 1e-10f);
}

__device__ __forceinline__ unsigned long long make_key(int a, float sc, int idx) {
  // higher key = earlier selection; ties -> lower orig idx (jnp.argmax).
  return (a >= 0)
      ? ((unsigned long long)__float_as_uint(sc) << 32) | (unsigned)(NN - 1 - idx)
      : 0ull;
}

// row base (u64 units) of element e in the triangular adj
__device__ __forceinline__ int adj_base(int e) {
  int W = e >> 6, l = e & 63;
  return 32 * W * (W + 1) + l * (W + 1);
}

// ------------- kernel 1: rank partials (8x8 chunks, 512 blocks) + adj zero --
__global__ __launch_bounds__(256) void k_rank(
    const int* __restrict__ agti_all,
    const float* __restrict__ prop_all,
    unsigned char* __restrict__ ws) {
  const int bidx = blockIdx.x;
  const int b = bidx >> 6;
  const int ec = (bidx >> 3) & 7, fc = bidx & 7;
  const int tid = threadIdx.x;
  const int* agti = agti_all + b * NN;
  const float* prop = prop_all + (size_t)b * NN * 5;
  unsigned char* W = ws + (size_t)b * IMG_STRIDE;

  // zero this image's adj (64 blocks per image cooperate)
  {
    unsigned long long* adj = (unsigned long long*)(W + OFF_ADJ);
    for (int t = ((bidx & 63) << 8) + tid; t < ADJ_U64; t += 64 * 256)
      adj[t] = 0ull;
  }

  __shared__ unsigned long long fkeys[TILE];
  const int f0 = fc << 8;
  {
    const int f = f0 + tid;
    fkeys[tid] = make_key(agti[f], prop[f * 5 + 4], f);
  }
  const int e = (ec << 8) + tid;
  const unsigned long long myk = make_key(agti[e], prop[e * 5 + 4], e);
  __syncthreads();

  int rank = 0;
  #pragma unroll 16
  for (int ff = 0; ff < TILE; ++ff) {
    unsigned long long kf = fkeys[ff];       // LDS broadcast
    int fi = f0 + ff;
    rank += (kf > myk || (kf == myk && fi < e)) ? 1 : 0;
  }
  ((unsigned short*)(W + OFF_RANKP))[(fc << 11) + e] = (unsigned short)rank;
}

// ------------- kernel 2: scatter to sorted slots + per-box prep -------------
__global__ __launch_bounds__(256) void k_scatter(
    const int* __restrict__ agti_all,
    const float* __restrict__ gtb_all,
    const float* __restrict__ prop_all,
    unsigned char* __restrict__ ws,
    float* __restrict__ out) {
  const int b = blockIdx.x >> 3, chunk = blockIdx.x & 7;
  const int tid = threadIdx.x;
  const int e = (chunk << 8) | tid;
  const int* agti = agti_all + b * NN;
  const float* prop = prop_all + (size_t)b * NN * 5;
  unsigned char* W = ws + (size_t)b * IMG_STRIDE;

  if (blockIdx.x == 0 && tid == 0) { out[0] = 0.f; out[1] = 0.f; }

  __shared__ float sgt[GG * 4];
  __shared__ int cnt4[4];
  sgt[tid] = gtb_all[b * GG * 4 + tid];

  const unsigned short* rp = (const unsigned short*)(W + OFF_RANKP);
  int rank = 0;
  #pragma unroll
  for (int fc = 0; fc < 8; ++fc) rank += rp[(fc << 11) + e];

  const int a = agti[e];
  const float sc = prop[e * 5 + 4];
  const bool pos = a >= 0;

  unsigned long long bal = __ballot(pos);
  if ((tid & 63) == 0) cnt4[tid >> 6] = __popcll(bal);
  __syncthreads();
  if (tid == 0)
    ((unsigned*)(W + OFF_NPOSP))[chunk] =
        (unsigned)(cnt4[0] + cnt4[1] + cnt4[2] + cnt4[3]);

  float4 bx = make_float4(0.f, 0.f, 0.f, 0.f);
  float gi = 0.f, pl = 0.f;
  if (pos) {
    bx = make_float4(prop[e * 5 + 0], prop[e * 5 + 1],
                     prop[e * 5 + 2], prop[e * 5 + 3]);
    gi = iou_pair(sgt[a * 4 + 0], sgt[a * 4 + 1], sgt[a * 4 + 2], sgt[a * 4 + 3],
                  bx.x, bx.y, bx.z, bx.w);
    pl = -logf(fminf(0.5f + fmaxf(gi, EPSF), 1.0f)) * sc;
  }
  ((float4*)(W + OFF_SBOX))[rank] = bx;
  ((float*)(W + OFF_GTPI))[rank] = gi;
  ((float*)(W + OFF_PULL))[rank] = pl;
  ((signed char*)(W + OFF_AGTI))[rank] = (signed char)a;
}

__device__ __forceinline__ int load_npos(const unsigned char* W) {
  const unsigned* np = (const unsigned*)(W + OFF_NPOSP);
  return (int)(np[0] + np[1] + np[2] + np[3] + np[4] + np[5] + np[6] + np[7]);
}

// ------------- kernel 3: tiled all-pairs (sorted) -> adj bitmask ------------
// Exact divide-free predicate:
// fl32(inter/denom) > 0.5f  <=>  (double)inter > (0.5+2^-25)*(double)denom
__global__ __launch_bounds__(256) void k_pairs(unsigned char* __restrict__ ws) {
  int bx = blockIdx.x;
  const int b = bx / (NPAIRT * 4);
  int rem = bx % (NPAIRT * 4);
  int p = rem >> 2;
  const int q = rem & 3;
  int r = 0;
  #pragma unroll
  for (int t = 0; t < NTILE; ++t) {
    int wdt = NTILE - t;
    if (p < wdt) { r = t; break; }
    p -= wdt;
  }
  const int c = r + p;
  const int tid = threadIdx.x;
  unsigned char* W = ws + (size_t)b * IMG_STRIDE;
  const float4* box = (const float4*)(W + OFF_SBOX);
  unsigned long long* adj = (unsigned long long*)(W + OFF_ADJ);
  const int npos = load_npos(W);

  const int jbase = c * TILE + q * CSLICE;
  if (jbase >= npos || r * TILE >= npos) return;   // uniform exits

  __shared__ float4 cbox[CSLICE];
  __shared__ float carea[CSLICE];

  if (tid < CSLICE) {
    float4 Bx = box[jbase + tid];
    cbox[tid] = Bx;
    carea[tid] = (Bx.z - Bx.x) * (Bx.w - Bx.y);
  }
  const int i = r * TILE + tid;
  const float4 A = box[i];
  const float area_a = (A.z - A.x) * (A.w - A.y);
  __syncthreads();

  const double THR = 0.5 + 0x1p-25;
  const unsigned long long ibit = 1ull << (i & 63);
  const int iw = i >> 6;
  #pragma unroll 8
  for (int jj = 0; jj < CSLICE; ++jj) {
    float4 Bx = cbox[jj];
    float ab = carea[jj];
    float lx = fmaxf(A.x, Bx.x), ly = fmaxf(A.y, Bx.y);
    float rx = fminf(A.z, Bx.z), ry = fminf(A.w, Bx.w);
    float w = fmaxf(rx - lx, 0.0f), h = fmaxf(ry - ly, 0.0f);
    float inter = w * h;
    float denom = area_a + ab - inter + 1e-10f;   // ((aa+ab)-inter)+eps
    int j = jbase + jj;
    bool hit = ((double)inter > THR * (double)denom) && (j > i) && (j < npos);
    if (hit) atomicOr(&adj[adj_base(j) + iw], ibit);
  }
}

// ------------- kernel 4: register-sweep resolve + bookkeeping + final -------
__global__ __launch_bounds__(512) void k_resolve(
    const float* __restrict__ gtb_all,
    unsigned char* __restrict__ ws,
    float* __restrict__ out) {
  const int b = blockIdx.x, tid = threadIdx.x;
  const int wave = tid >> 6, lane = tid & 63;
  unsigned char* W = ws + (size_t)b * IMG_STRIDE;
  const float* gtpi = (const float*)(W + OFF_GTPI);
  const float* pull = (const float*)(W + OFF_PULL);
  const signed char* ag8 = (const signed char*)(W + OFF_AGTI);
  const unsigned long long* adj = (const unsigned long long*)(W + OFF_ADJ);
  const int npos = load_npos(W);

  __shared__ unsigned long long selw[32];
  __shared__ int minselg[GG], bestposg[GG];
  __shared__ int s_maxsel, s_hasrem;
  __shared__ float wtp[8];

  if (tid == 0) { s_maxsel = -1; s_hasrem = 0; }
  if (tid < GG) { minselg[tid] = NN; bestposg[tid] = NN; }
  __syncthreads();

  // ---- ordered sweep, sel[] in registers (constant-indexed only) ----
  if (wave == 0) {
    unsigned long long sel[32];
    #pragma unroll
    for (int w = 0; w < 32; ++w) {
      const int e = (w << 6) | lane;
      const bool pos = e < npos;
      // triangular row of e: words 0..w
      const unsigned long long* row = adj + ((w * (w + 1)) << 5) + lane * (w + 1);
      unsigned long long intra = pos ? row[w] : 0ull;   // same-word killers
      bool ckill = false;
      #pragma unroll
      for (int wp = 0; wp < w; ++wp)
        ckill |= pos && ((row[wp] & sel[wp]) != 0ull);
      const bool alive0 = pos && !ckill;
      bool alive = alive0;
      unsigned long long bal = __ballot(alive), prev;
      do {
        prev = bal;
        alive = alive0 && ((intra & bal) == 0ull);
        bal = __ballot(alive);
      } while (bal != prev);
      sel[w] = bal;
      if (lane == 0) selw[w] = bal;
    }
  }
  __syncthreads();

  // ---- bookkeeping pass 1 ----
  float tp_part = 0.f;
  int maxsel_p = -1;
  #pragma unroll
  for (int k = 0; k < 4; ++k) {
    int e = tid + (k << 9);
    if (e < npos) {
      int g = ag8[e];
      atomicMin(&bestposg[g], e);
      bool sel = (selw[e >> 6] >> (e & 63)) & 1ull;
      if (sel) {
        atomicMin(&minselg[g], e);
        tp_part += pull[e];
        maxsel_p = e > maxsel_p ? e : maxsel_p;
      }
    }
  }
  #pragma unroll
  for (int off = 32; off; off >>= 1) {
    int o = __shfl_xor(maxsel_p, off, 64);
    maxsel_p = o > maxsel_p ? o : maxsel_p;
  }
  if (lane == 0) atomicMax(&s_maxsel, maxsel_p);
  __syncthreads();

  // ---- pass 2: first-of-g subtraction; has_rem for last selection ----
  const int idx_last = s_maxsel;
  const int lw = idx_last >> 6;
  const unsigned long long lmask = ~(1ull << (idx_last & 63));
  #pragma unroll
  for (int k = 0; k < 4; ++k) {
    int e = tid + (k << 9);
    if (e >= npos) continue;
    bool sel = (selw[e >> 6] >> (e & 63)) & 1ull;
    if (sel) {
      if (e == minselg[ag8[e]]) tp_part -= pull[e];   // first of its g
    } else {
      // killed box: active at i_last's turn iff its ONLY selected killer is
      // i_last  => no selected killer other than idx_last.
      const unsigned long long* row = adj + adj_base(e);
      const int We = e >> 6;
      unsigned long long om = 0ull;
      for (int wp = 0; wp <= We; ++wp) {
        unsigned long long m = row[wp] & selw[wp];
        if (wp == lw) m &= lmask;
        om |= m;
      }
      if (om == 0ull) s_hasrem = 1;
    }
  }
  #pragma unroll
  for (int off = 32; off; off >>= 1) tp_part += __shfl_xor(tp_part, off, 64);
  if (lane == 0) wtp[wave] = tp_part;
  __syncthreads();

  // ---- push + finalize (wave 0; lane == g) ----
  if (wave == 0) {
    float mypush = 0.f;
    int mycnt2 = 0;
    int bp = bestposg[lane];
    bool seen = minselg[lane] < NN;
    if (bp < NN) {
      float h = gtb_all[b * GG * 4 + lane * 4 + 3] - gtb_all[b * GG * 4 + lane * 4 + 1];
      if (h >= MIN_H && !seen) { mypush = 1.0f - gtpi[bp]; mycnt2 = 1; }
    }
    #pragma unroll
    for (int off = 32; off; off >>= 1) {
      mypush += __shfl_xor(mypush, off, 64);
      mycnt2 += __shfl_xor(mycnt2, off, 64);
    }
    if (lane == 0) {
      float tp = 0.f;
      #pragma unroll
      for (int w = 0; w < 8; ++w) tp += wtp[w];
      int total_sel = 0;
      for (int w = 0; w < 32; ++w) total_sel += __popcll(selw[w]);
      int distinct = 0;
      for (int g = 0; g < GG; ++g) distinct += (minselg[g] < NN) ? 1 : 0;
      int pc = total_sel - distinct;
      if (idx_last >= 0) {
        int gl = ag8[idx_last];
        // last selection's pull counts only if non-first-of-g AND has_rem
        if (idx_last != minselg[gl] && !s_hasrem) tp -= pull[idx_last];
      }
      float push_loss = 0.f, pull_loss = 0.f;
      if (npos > 1) {
        pull_loss = tp / ((float)pc + EPSF);
        push_loss = mypush / ((float)mycnt2 + EPSF);
      }
      atomicAdd(&out[0], push_loss * (1.0f / B_IMG));
      atomicAdd(&out[1], pull_loss * (1.0f / B_IMG));
    }
  }
}

extern "C" void kernel_launch(void* const* d_in, const int* in_sizes, int n_in,
                              void* d_out, int out_size, void* d_ws, size_t ws_size,
                              hipStream_t stream) {
  const int* agti = (const int*)d_in[1];
  const float* gtb = (const float*)d_in[2];
  const float* prop = (const float*)d_in[3];
  unsigned char* ws = (unsigned char*)d_ws;
  float* out = (float*)d_out;

  k_rank<<<B_IMG * 64, 256, 0, stream>>>(agti, prop, ws);
  k_scatter<<<B_IMG * 8, 256, 0, stream>>>(agti, gtb, prop, ws, out);
  k_pairs<<<B_IMG * NPAIRT * 4, 256, 0, stream>>>(ws);
  k_resolve<<<B_IMG, 512, 0, stream>>>(gtb, ws, out);
}

// Round 11
// 61.402 us; speedup vs baseline: 1.7979x; 1.7979x over previous
//
#include <hip/hip_runtime.h>
#include <math.h>

// NMSLoss4: B=8, N=2048, G=64. Key-sorted (desc) space: every killer of e has
// index < e, so an ordered sweep gives the exact sequential-NMS fixed point.
// Round 10: blocked Gauss-Seidel sweep with DISTRIBUTED kill accumulation —
// after word w commits, all 512 threads fold column w of the triangular
// adjacency into their owned elements' kill registers (column prefetched one
// step ahead). Commit itself is register+ballot only. One barrier per step.
// has_rem pass reduced to elements e > idx_last (provably sufficient).

#define B_IMG 8
#define NN 2048
#define GG 64
#define MIN_H 50.0f
#define EPSF 1e-6f
#define TILE 256
#define NTILE 8
#define NPAIRT 36            // triangular 256x256 tile pairs
#define CSLICE 64
#define ADJ_U64 33792        // sum over words W: 64*(W+1), W=0..31

// per-image ws layout (bytes)
#define OFF_SBOX  0          // float4[2048]                 32768
#define OFF_GTPI  32768      // f32[2048]                     8192
#define OFF_PULL  40960      // f32[2048]                     8192
#define OFF_AGTI  49152      // s8[2048]                      2048
#define OFF_NPOSP 51200      // u32[8] per-chunk counts (+pad)
#define OFF_RANKP 51456      // u16[8][2048]                 32768
#define OFF_ADJ   84224      // u64[33792] triangular       270336
#define IMG_STRIDE 354560

__device__ __forceinline__ float iou_pair(
    float ax1, float ay1, float ax2, float ay2,
    float bx1, float by1, float bx2, float by2) {
  float area_a = (ax2 - ax1) * (ay2 - ay1);
  float area_b = (bx2 - bx1) * (by2 - by1);
  float lx = fmaxf(ax1, bx1), ly = fmaxf(ay1, by1);
  float rx = fminf(ax2, bx2), ry = fminf(ay2, by2);
  float w = fmaxf(rx - lx, 0.0f), h = fmaxf(ry - ly, 0.0f);
  float inter = w * h;
  return inter / (area_a + area_b - inter + 1e-10f);
}

__device__ __forceinline__ unsigned long long make_key(int a, float sc, int idx) {
  // higher key = earlier selection; ties -> lower orig idx (jnp.argmax).
  return (a >= 0)
      ? ((unsigned long long)__float_as_uint(sc) << 32) | (unsigned)(NN - 1 - idx)
      : 0ull;
}

// row base (u64 units) of element e in the triangular adj
__device__ __forceinline__ int adj_base(int e) {
  int W = e >> 6, l = e & 63;
  return 32 * W * (W + 1) + l * (W + 1);
}

// ------------- kernel 1: rank partials (8x8 chunks, 512 blocks) + adj zero --
__global__ __launch_bounds__(256) void k_rank(
    const int* __restrict__ agti_all,
    const float* __restrict__ prop_all,
    unsigned char* __restrict__ ws) {
  const int bidx = blockIdx.x;
  const int b = bidx >> 6;
  const int ec = (bidx >> 3) & 7, fc = bidx & 7;
  const int tid = threadIdx.x;
  const int* agti = agti_all + b * NN;
  const float* prop = prop_all + (size_t)b * NN * 5;
  unsigned char* W = ws + (size_t)b * IMG_STRIDE;

  // zero this image's adj (64 blocks per image cooperate)
  {
    unsigned long long* adj = (unsigned long long*)(W + OFF_ADJ);
    for (int t = ((bidx & 63) << 8) + tid; t < ADJ_U64; t += 64 * 256)
      adj[t] = 0ull;
  }

  __shared__ unsigned long long fkeys[TILE];
  const int f0 = fc << 8;
  {
    const int f = f0 + tid;
    fkeys[tid] = make_key(agti[f], prop[f * 5 + 4], f);
  }
  const int e = (ec << 8) + tid;
  const unsigned long long myk = make_key(agti[e], prop[e * 5 + 4], e);
  __syncthreads();

  int rank = 0;
  #pragma unroll 16
  for (int ff = 0; ff < TILE; ++ff) {
    unsigned long long kf = fkeys[ff];       // LDS broadcast
    int fi = f0 + ff;
    rank += (kf > myk || (kf == myk && fi < e)) ? 1 : 0;
  }
  ((unsigned short*)(W + OFF_RANKP))[(fc << 11) + e] = (unsigned short)rank;
}

// ------------- kernel 2: scatter to sorted slots + per-box prep -------------
__global__ __launch_bounds__(256) void k_scatter(
    const int* __restrict__ agti_all,
    const float* __restrict__ gtb_all,
    const float* __restrict__ prop_all,
    unsigned char* __restrict__ ws,
    float* __restrict__ out) {
  const int b = blockIdx.x >> 3, chunk = blockIdx.x & 7;
  const int tid = threadIdx.x;
  const int e = (chunk << 8) | tid;
  const int* agti = agti_all + b * NN;
  const float* prop = prop_all + (size_t)b * NN * 5;
  unsigned char* W = ws + (size_t)b * IMG_STRIDE;

  if (blockIdx.x == 0 && tid == 0) { out[0] = 0.f; out[1] = 0.f; }

  __shared__ float sgt[GG * 4];
  __shared__ int cnt4[4];
  sgt[tid] = gtb_all[b * GG * 4 + tid];

  const unsigned short* rp = (const unsigned short*)(W + OFF_RANKP);
  int rank = 0;
  #pragma unroll
  for (int fc = 0; fc < 8; ++fc) rank += rp[(fc << 11) + e];

  const int a = agti[e];
  const float sc = prop[e * 5 + 4];
  const bool pos = a >= 0;

  unsigned long long bal = __ballot(pos);
  if ((tid & 63) == 0) cnt4[tid >> 6] = __popcll(bal);
  __syncthreads();
  if (tid == 0)
    ((unsigned*)(W + OFF_NPOSP))[chunk] =
        (unsigned)(cnt4[0] + cnt4[1] + cnt4[2] + cnt4[3]);

  float4 bx = make_float4(0.f, 0.f, 0.f, 0.f);
  float gi = 0.f, pl = 0.f;
  if (pos) {
    bx = make_float4(prop[e * 5 + 0], prop[e * 5 + 1],
                     prop[e * 5 + 2], prop[e * 5 + 3]);
    gi = iou_pair(sgt[a * 4 + 0], sgt[a * 4 + 1], sgt[a * 4 + 2], sgt[a * 4 + 3],
                  bx.x, bx.y, bx.z, bx.w);
    pl = -logf(fminf(0.5f + fmaxf(gi, EPSF), 1.0f)) * sc;
  }
  ((float4*)(W + OFF_SBOX))[rank] = bx;
  ((float*)(W + OFF_GTPI))[rank] = gi;
  ((float*)(W + OFF_PULL))[rank] = pl;
  ((signed char*)(W + OFF_AGTI))[rank] = (signed char)a;
}

__device__ __forceinline__ int load_npos(const unsigned char* W) {
  const unsigned* np = (const unsigned*)(W + OFF_NPOSP);
  return (int)(np[0] + np[1] + np[2] + np[3] + np[4] + np[5] + np[6] + np[7]);
}

// ------------- kernel 3: tiled all-pairs (sorted) -> adj bitmask ------------
// Exact divide-free predicate:
// fl32(inter/denom) > 0.5f  <=>  (double)inter > (0.5+2^-25)*(double)denom
__global__ __launch_bounds__(256) void k_pairs(unsigned char* __restrict__ ws) {
  int bx = blockIdx.x;
  const int b = bx / (NPAIRT * 4);
  int rem = bx % (NPAIRT * 4);
  int p = rem >> 2;
  const int q = rem & 3;
  int r = 0;
  #pragma unroll
  for (int t = 0; t < NTILE; ++t) {
    int wdt = NTILE - t;
    if (p < wdt) { r = t; break; }
    p -= wdt;
  }
  const int c = r + p;
  const int tid = threadIdx.x;
  unsigned char* W = ws + (size_t)b * IMG_STRIDE;
  const float4* box = (const float4*)(W + OFF_SBOX);
  unsigned long long* adj = (unsigned long long*)(W + OFF_ADJ);
  const int npos = load_npos(W);

  const int jbase = c * TILE + q * CSLICE;
  if (jbase >= npos || r * TILE >= npos) return;   // uniform exits

  __shared__ float4 cbox[CSLICE];
  __shared__ float carea[CSLICE];

  if (tid < CSLICE) {
    float4 Bx = box[jbase + tid];
    cbox[tid] = Bx;
    carea[tid] = (Bx.z - Bx.x) * (Bx.w - Bx.y);
  }
  const int i = r * TILE + tid;
  const float4 A = box[i];
  const float area_a = (A.z - A.x) * (A.w - A.y);
  __syncthreads();

  const double THR = 0.5 + 0x1p-25;
  const unsigned long long ibit = 1ull << (i & 63);
  const int iw = i >> 6;
  #pragma unroll 8
  for (int jj = 0; jj < CSLICE; ++jj) {
    float4 Bx = cbox[jj];
    float ab = carea[jj];
    float lx = fmaxf(A.x, Bx.x), ly = fmaxf(A.y, Bx.y);
    float rx = fminf(A.z, Bx.z), ry = fminf(A.w, Bx.w);
    float w = fmaxf(rx - lx, 0.0f), h = fmaxf(ry - ly, 0.0f);
    float inter = w * h;
    float denom = area_a + ab - inter + 1e-10f;   // ((aa+ab)-inter)+eps
    int j = jbase + jj;
    bool hit = ((double)inter > THR * (double)denom) && (j > i) && (j < npos);
    if (hit) atomicOr(&adj[adj_base(j) + iw], ibit);
  }
}

// ------------- kernel 4: distributed-sweep resolve + bookkeeping + final ----
__global__ __launch_bounds__(512) void k_resolve(
    const float* __restrict__ gtb_all,
    unsigned char* __restrict__ ws,
    float* __restrict__ out) {
  const int b = blockIdx.x, tid = threadIdx.x;
  const int wave = tid >> 6, lane = tid & 63;
  unsigned char* W = ws + (size_t)b * IMG_STRIDE;
  const float* gtpi = (const float*)(W + OFF_GTPI);
  const float* pull = (const float*)(W + OFF_PULL);
  const signed char* ag8 = (const signed char*)(W + OFF_AGTI);
  const unsigned long long* adj = (const unsigned long long*)(W + OFF_ADJ);
  const int npos = load_npos(W);

  __shared__ unsigned long long selw[32];
  __shared__ int minselg[GG], bestposg[GG];
  __shared__ int s_maxsel, s_hasrem;
  __shared__ float wtp[8];

  if (tid == 0) { s_maxsel = -1; s_hasrem = 0; }
  if (tid < GG) { minselg[tid] = NN; bestposg[tid] = NN; }

  // thread owns elements e = tid + k*512, word myW[k] = k*8 + wave.
  // word w is committed by wave (w&7), slot k = w>>3.
  const unsigned long long* rowp[4];
  unsigned long long diag[4], colbuf[4], kill[4];
  int myW[4];
  #pragma unroll
  for (int k = 0; k < 4; ++k) {
    const int e = tid + (k << 9);
    myW[k] = (k << 3) + wave;
    rowp[k] = adj + adj_base(e);
    diag[k] = rowp[k][myW[k]];                    // intra-word killer mask
    kill[k] = 0ull;
    colbuf[k] = (myW[k] > 0) ? rowp[k][0] : 0ull; // prefetch column 0
  }
  __syncthreads();

  // ---- blocked Gauss-Seidel sweep: one barrier per word step ----
  #pragma unroll
  for (int w = 0; w < 32; ++w) {
    if (wave == (w & 7)) {
      const int k = w >> 3;                      // compile-time
      const int e = (w << 6) | lane;
      const bool alive0 = (e < npos) && (kill[k] == 0ull);
      const unsigned long long intra = diag[k];  // only bits < lane set
      bool alive = alive0;
      unsigned long long bal = __ballot(alive), prev;
      do {
        prev = bal;
        alive = alive0 && ((intra & bal) == 0ull);
        bal = __ballot(alive);
      } while (bal != prev);
      if (lane == 0) selw[w] = bal;
    }
    __syncthreads();                             // selw[w] visible to all
    const unsigned long long sw = selw[w];
    #pragma unroll
    for (int k = 0; k < 4; ++k) {
      if (myW[k] > w) kill[k] |= colbuf[k] & sw; // fold column w
      colbuf[k] = (myW[k] > w + 1) ? rowp[k][w + 1] : 0ull; // prefetch next
    }
  }
  __syncthreads();

  // ---- bookkeeping pass 1 ----
  float tp_part = 0.f;
  int maxsel_p = -1;
  #pragma unroll
  for (int k = 0; k < 4; ++k) {
    int e = tid + (k << 9);
    if (e < npos) {
      int g = ag8[e];
      atomicMin(&bestposg[g], e);
      bool sel = (selw[e >> 6] >> (e & 63)) & 1ull;
      if (sel) {
        atomicMin(&minselg[g], e);
        tp_part += pull[e];
        maxsel_p = e > maxsel_p ? e : maxsel_p;
      }
    }
  }
  #pragma unroll
  for (int off = 32; off; off >>= 1) {
    int o = __shfl_xor(maxsel_p, off, 64);
    maxsel_p = o > maxsel_p ? o : maxsel_p;
  }
  if (lane == 0) atomicMax(&s_maxsel, maxsel_p);
  __syncthreads();

  // ---- pass 2: first-of-g subtraction; has_rem (only e > idx_last can have
  // idx_last as a killer, and all such e are killed) ----
  const int idx_last = s_maxsel;
  if (idx_last >= 0) {
    const int lw = idx_last >> 6;
    const unsigned long long lmask = ~(1ull << (idx_last & 63));
    #pragma unroll
    for (int k = 0; k < 4; ++k) {
      int e = tid + (k << 9);
      if (e < npos) {
        bool sel = (selw[e >> 6] >> (e & 63)) & 1ull;
        if (sel) {
          if (e == minselg[ag8[e]]) tp_part -= pull[e];   // first of its g
        } else if (e > idx_last) {
          // killed; active at i_last's turn iff only selected killer is i_last
          unsigned long long om = 0ull;
          const unsigned long long* row = rowp[k];
          const int We = myW[k];
          #pragma unroll
          for (int wp = 0; wp < 32; ++wp) {
            if (wp <= We) {
              unsigned long long m = row[wp] & selw[wp];
              if (wp == lw) m &= lmask;
              om |= m;
            }
          }
          if (om == 0ull) s_hasrem = 1;
        }
      }
    }
  }
  #pragma unroll
  for (int off = 32; off; off >>= 1) tp_part += __shfl_xor(tp_part, off, 64);
  if (lane == 0) wtp[wave] = tp_part;
  __syncthreads();

  // ---- push + finalize (wave 0; lane == g) ----
  if (wave == 0) {
    float mypush = 0.f;
    int mycnt2 = 0;
    int bp = bestposg[lane];
    bool seen = minselg[lane] < NN;
    if (bp < NN) {
      float h = gtb_all[b * GG * 4 + lane * 4 + 3] - gtb_all[b * GG * 4 + lane * 4 + 1];
      if (h >= MIN_H && !seen) { mypush = 1.0f - gtpi[bp]; mycnt2 = 1; }
    }
    #pragma unroll
    for (int off = 32; off; off >>= 1) {
      mypush += __shfl_xor(mypush, off, 64);
      mycnt2 += __shfl_xor(mycnt2, off, 64);
    }
    if (lane == 0) {
      float tp = 0.f;
      #pragma unroll
      for (int w = 0; w < 8; ++w) tp += wtp[w];
      int total_sel = 0;
      for (int w = 0; w < 32; ++w) total_sel += __popcll(selw[w]);
      int distinct = 0;
      for (int g = 0; g < GG; ++g) distinct += (minselg[g] < NN) ? 1 : 0;
      int pc = total_sel - distinct;
      if (idx_last >= 0) {
        int gl = ag8[idx_last];
        // last selection's pull counts only if non-first-of-g AND has_rem
        if (idx_last != minselg[gl] && !s_hasrem) tp -= pull[idx_last];
      }
      float push_loss = 0.f, pull_loss = 0.f;
      if (npos > 1) {
        pull_loss = tp / ((float)pc + EPSF);
        push_loss = mypush / ((float)mycnt2 + EPSF);
      }
      atomicAdd(&out[0], push_loss * (1.0f / B_IMG));
      atomicAdd(&out[1], pull_loss * (1.0f / B_IMG));
    }
  }
}

extern "C" void kernel_launch(void* const* d_in, const int* in_sizes, int n_in,
                              void* d_out, int out_size, void* d_ws, size_t ws_size,
                              hipStream_t stream) {
  const int* agti = (const int*)d_in[1];
  const float* gtb = (const float*)d_in[2];
  const float* prop = (const float*)d_in[3];
  unsigned char* ws = (unsigned char*)d_ws;
  float* out = (float*)d_out;

  k_rank<<<B_IMG * 64, 256, 0, stream>>>(agti, prop, ws);
  k_scatter<<<B_IMG * 8, 256, 0, stream>>>(agti, gtb, prop, ws, out);
  k_pairs<<<B_IMG * NPAIRT * 4, 256, 0, stream>>>(ws);
  k_resolve<<<B_IMG, 512, 0, stream>>>(gtb, ws, out);
}

// Round 12
// 57.142 us; speedup vs baseline: 1.9319x; 1.0745x over previous
//
#include <hip/hip_runtime.h>
#include <math.h>

// NMSLoss4: B=8, N=2048, G=64. Key-sorted (desc) space: every killer of e has
// index < e, so an ordered blocked Gauss-Seidel sweep with distributed column
// folding gives the exact sequential-NMS fixed point (round 10/11 structure).
// Round 11: k_scatter eliminated (3 dispatches) — per-element data stays in
// ORIGINAL order; adj edges written at RANK coordinates in k_pairs; k_resolve
// rebuilds perm[rank]=orig from rank partials. Sweep column prefetch 2-deep.

#define B_IMG 8
#define NN 2048
#define GG 64
#define MIN_H 50.0f
#define EPSF 1e-6f
#define TILE 256
#define NTILE 8
#define NPAIRT 36            // triangular 256x256 tile pairs
#define CSLICE 64
#define ADJ_U64 33792        // sum over words W: 64*(W+1), W=0..31

// per-image ws layout (bytes) — all per-element arrays in ORIGINAL order
#define OFF_BOXO  0          // float4[2048]                 32768
#define OFF_GTPIO 32768      // f32[2048]                     8192
#define OFF_PULLO 40960      // f32[2048]                     8192
#define OFF_AGTIO 49152      // s8[2048]                      2048
#define OFF_NPOSP 51200      // u32[8] per-chunk counts (+pad)
#define OFF_RANKP 51456      // u16[8][2048]                 32768
#define OFF_ADJ   84224      // u64[33792] triangular (rank space) 270336
#define IMG_STRIDE 354560

__device__ __forceinline__ float iou_pair(
    float ax1, float ay1, float ax2, float ay2,
    float bx1, float by1, float bx2, float by2) {
  float area_a = (ax2 - ax1) * (ay2 - ay1);
  float area_b = (bx2 - bx1) * (by2 - by1);
  float lx = fmaxf(ax1, bx1), ly = fmaxf(ay1, by1);
  float rx = fminf(ax2, bx2), ry = fminf(ay2, by2);
  float w = fmaxf(rx - lx, 0.0f), h = fmaxf(ry - ly, 0.0f);
  float inter = w * h;
  return inter / (area_a + area_b - inter + 1e-10f);
}

__device__ __forceinline__ unsigned long long make_key(int a, float sc, int idx) {
  // higher key = earlier selection; ties -> lower orig idx (jnp.argmax).
  return (a >= 0)
      ? ((unsigned long long)__float_as_uint(sc) << 32) | (unsigned)(NN - 1 - idx)
      : 0ull;
}

// row base (u64 units) of rank-space element e in the triangular adj
__device__ __forceinline__ int adj_base(int e) {
  int W = e >> 6, l = e & 63;
  return 32 * W * (W + 1) + l * (W + 1);
}

// ------------- kernel 1: rank partials + per-elem prep + adj zero -----------
__global__ __launch_bounds__(256) void k_rank(
    const int* __restrict__ agti_all,
    const float* __restrict__ gtb_all,
    const float* __restrict__ prop_all,
    unsigned char* __restrict__ ws,
    float* __restrict__ out) {
  const int bidx = blockIdx.x;
  const int b = bidx >> 6;
  const int ec = (bidx >> 3) & 7, fc = bidx & 7;
  const int tid = threadIdx.x;
  const int* agti = agti_all + b * NN;
  const float* prop = prop_all + (size_t)b * NN * 5;
  unsigned char* W = ws + (size_t)b * IMG_STRIDE;

  if (bidx == 0 && tid == 0) { out[0] = 0.f; out[1] = 0.f; }

  // zero this image's adj (64 blocks per image cooperate)
  {
    unsigned long long* adj = (unsigned long long*)(W + OFF_ADJ);
    for (int t = ((bidx & 63) << 8) + tid; t < ADJ_U64; t += 64 * 256)
      adj[t] = 0ull;
  }

  __shared__ unsigned long long fkeys[TILE];
  __shared__ float sgt[GG * 4];
  __shared__ int cnt4[4];

  const int f0 = fc << 8;
  {
    const int f = f0 + tid;
    fkeys[tid] = make_key(agti[f], prop[f * 5 + 4], f);
  }
  if (fc == 0) sgt[tid] = gtb_all[b * GG * 4 + tid];

  const int e = (ec << 8) + tid;
  const int a = agti[e];
  const float sc = prop[e * 5 + 4];
  const unsigned long long myk = make_key(a, sc, e);
  const bool pos = a >= 0;
  {
    unsigned long long bal = __ballot(pos);
    if ((tid & 63) == 0) cnt4[tid >> 6] = __popcll(bal);
  }
  __syncthreads();

  int rank = 0;
  #pragma unroll 16
  for (int ff = 0; ff < TILE; ++ff) {
    unsigned long long kf = fkeys[ff];       // LDS broadcast
    int fi = f0 + ff;
    rank += (kf > myk || (kf == myk && fi < e)) ? 1 : 0;
  }
  ((unsigned short*)(W + OFF_RANKP))[(fc << 11) + e] = (unsigned short)rank;

  if (fc == 0) {
    // per-element prep in ORIGINAL order + chunk positive count
    float4 bx = make_float4(prop[e * 5 + 0], prop[e * 5 + 1],
                            prop[e * 5 + 2], prop[e * 5 + 3]);
    float gi = 0.f, pl = 0.f;
    if (pos) {
      gi = iou_pair(sgt[a * 4 + 0], sgt[a * 4 + 1], sgt[a * 4 + 2], sgt[a * 4 + 3],
                    bx.x, bx.y, bx.z, bx.w);
      pl = -logf(fminf(0.5f + fmaxf(gi, EPSF), 1.0f)) * sc;
    }
    ((float4*)(W + OFF_BOXO))[e] = bx;
    ((float*)(W + OFF_GTPIO))[e] = gi;
    ((float*)(W + OFF_PULLO))[e] = pl;
    ((signed char*)(W + OFF_AGTIO))[e] = (signed char)a;
    if (tid == 0)
      ((unsigned*)(W + OFF_NPOSP))[ec] =
          (unsigned)(cnt4[0] + cnt4[1] + cnt4[2] + cnt4[3]);
  }
}

__device__ __forceinline__ int load_npos(const unsigned char* W) {
  const unsigned* np = (const unsigned*)(W + OFF_NPOSP);
  return (int)(np[0] + np[1] + np[2] + np[3] + np[4] + np[5] + np[6] + np[7]);
}

// ------------- kernel 2: tiled all-pairs (orig space) -> adj @ rank coords --
// Exact divide-free predicate:
// fl32(inter/denom) > 0.5f  <=>  (double)inter > (0.5+2^-25)*(double)denom
// Edge direction by rank: killer = smaller rank. Negatives rank >= npos, so
// they can only be victims (rows never read by the sweep) — no pos check.
__global__ __launch_bounds__(256) void k_pairs(unsigned char* __restrict__ ws) {
  int bx = blockIdx.x;
  const int b = bx / (NPAIRT * 4);
  int rem = bx % (NPAIRT * 4);
  int p = rem >> 2;
  const int q = rem & 3;
  int r = 0;
  #pragma unroll
  for (int t = 0; t < NTILE; ++t) {
    int wdt = NTILE - t;
    if (p < wdt) { r = t; break; }
    p -= wdt;
  }
  const int c = r + p;
  const int tid = threadIdx.x;
  unsigned char* W = ws + (size_t)b * IMG_STRIDE;
  const float4* box = (const float4*)(W + OFF_BOXO);
  const unsigned short* rp = (const unsigned short*)(W + OFF_RANKP);
  unsigned long long* adj = (unsigned long long*)(W + OFF_ADJ);

  __shared__ float4 cbox[CSLICE];
  __shared__ float carea[CSLICE];
  __shared__ unsigned short crank[CSLICE];

  const int jbase = c * TILE + q * CSLICE;
  if (tid < CSLICE) {
    int j = jbase + tid;
    float4 Bx = box[j];
    cbox[tid] = Bx;
    carea[tid] = (Bx.z - Bx.x) * (Bx.w - Bx.y);
    int rj = 0;
    #pragma unroll
    for (int fc = 0; fc < 8; ++fc) rj += rp[(fc << 11) + j];
    crank[tid] = (unsigned short)rj;
  }
  const int i = r * TILE + tid;
  const float4 A = box[i];
  const float area_a = (A.z - A.x) * (A.w - A.y);
  int ri = 0;
  #pragma unroll
  for (int fc = 0; fc < 8; ++fc) ri += rp[(fc << 11) + i];
  __syncthreads();

  const double THR = 0.5 + 0x1p-25;
  #pragma unroll 8
  for (int jj = 0; jj < CSLICE; ++jj) {
    float4 Bx = cbox[jj];
    float ab = carea[jj];
    float lx = fmaxf(A.x, Bx.x), ly = fmaxf(A.y, Bx.y);
    float rx = fminf(A.z, Bx.z), ry = fminf(A.w, Bx.w);
    float w = fmaxf(rx - lx, 0.0f), h = fmaxf(ry - ly, 0.0f);
    float inter = w * h;
    float denom = area_a + ab - inter + 1e-10f;   // ((aa+ab)-inter)+eps
    int j = jbase + jj;
    bool hit = ((double)inter > THR * (double)denom) && (j > i);
    if (hit) {
      int rj = crank[jj];
      int rv = ri > rj ? ri : rj;     // victim = larger rank
      int rk = ri > rj ? rj : ri;     // killer = smaller rank
      atomicOr(&adj[adj_base(rv) + (rk >> 6)], 1ull << (rk & 63));
    }
  }
}

// ------------- kernel 3: perm build + distributed sweep + bookkeeping -------
__global__ __launch_bounds__(512) void k_resolve(
    const float* __restrict__ gtb_all,
    unsigned char* __restrict__ ws,
    float* __restrict__ out) {
  const int b = blockIdx.x, tid = threadIdx.x;
  const int wave = tid >> 6, lane = tid & 63;
  unsigned char* W = ws + (size_t)b * IMG_STRIDE;
  const float* gtpiO = (const float*)(W + OFF_GTPIO);
  const float* pullO = (const float*)(W + OFF_PULLO);
  const signed char* agO = (const signed char*)(W + OFF_AGTIO);
  const unsigned long long* adj = (const unsigned long long*)(W + OFF_ADJ);
  const int npos = load_npos(W);

  __shared__ unsigned short perm[NN];          // sorted(rank) -> orig
  __shared__ unsigned long long selw[32];
  __shared__ int minselg[GG], bestposg[GG];
  __shared__ int s_maxsel, s_hasrem;
  __shared__ float wtp[8];

  // thread owns sorted elements e = tid + k*512, word myW[k] = k*8 + wave.
  // word w committed by wave (w&7), slot k = w>>3. Columns prefetched 2-deep.
  const unsigned long long* rowp[4];
  unsigned long long diag[4], cb0[4], cb1[4], kill[4];
  int myW[4];
  #pragma unroll
  for (int k = 0; k < 4; ++k) {
    const int e = tid + (k << 9);
    myW[k] = (k << 3) + wave;
    rowp[k] = adj + adj_base(e);
    diag[k] = rowp[k][myW[k]];                    // intra-word killer mask
    kill[k] = 0ull;
    cb0[k] = (myW[k] > 0) ? rowp[k][0] : 0ull;    // column 0 (even slot)
    cb1[k] = (myW[k] > 1) ? rowp[k][1] : 0ull;    // column 1 (odd slot)
  }

  // perm: orig -> rank from partials, scatter into LDS
  {
    const unsigned short* rp = (const unsigned short*)(W + OFF_RANKP);
    #pragma unroll
    for (int k = 0; k < 4; ++k) {
      int o = tid + (k << 9);                    // original index
      int rank = 0;
      #pragma unroll
      for (int fc = 0; fc < 8; ++fc) rank += rp[(fc << 11) + o];
      perm[rank] = (unsigned short)o;
    }
  }
  if (tid == 0) { s_maxsel = -1; s_hasrem = 0; }
  if (tid < GG) { minselg[tid] = NN; bestposg[tid] = NN; }
  __syncthreads();

  // gather per-owned-sorted-element data through perm
  float mypull[4];
  int myag[4];
  #pragma unroll
  for (int k = 0; k < 4; ++k) {
    int e = tid + (k << 9);
    int o = perm[e];
    mypull[k] = pullO[o];
    myag[k] = agO[o];
  }

  // ---- blocked Gauss-Seidel sweep: one barrier per word step ----
  #pragma unroll
  for (int w = 0; w < 32; ++w) {
    if (wave == (w & 7)) {
      const int k = w >> 3;                      // compile-time
      const int e = (w << 6) | lane;
      const bool alive0 = (e < npos) && (kill[k] == 0ull);
      const unsigned long long intra = diag[k];  // only bits < lane set
      bool alive = alive0;
      unsigned long long bal = __ballot(alive), prev;
      do {
        prev = bal;
        alive = alive0 && ((intra & bal) == 0ull);
        bal = __ballot(alive);
      } while (bal != prev);
      if (lane == 0) selw[w] = bal;
    }
    __syncthreads();                             // selw[w] visible to all
    const unsigned long long sw = selw[w];
    #pragma unroll
    for (int k = 0; k < 4; ++k) {
      unsigned long long cur = ((w & 1) == 0) ? cb0[k] : cb1[k];  // column w
      if (myW[k] > w) kill[k] |= cur & sw;       // fold column w
      unsigned long long nxt = (myW[k] > w + 2) ? rowp[k][w + 2] : 0ull;
      if ((w & 1) == 0) cb0[k] = nxt; else cb1[k] = nxt;          // prefetch
    }
  }
  __syncthreads();

  // ---- bookkeeping pass 1 ----
  float tp_part = 0.f;
  int maxsel_p = -1;
  #pragma unroll
  for (int k = 0; k < 4; ++k) {
    int e = tid + (k << 9);
    if (e < npos) {
      int g = myag[k];                           // e<npos => positive
      atomicMin(&bestposg[g], e);
      bool sel = (selw[e >> 6] >> (e & 63)) & 1ull;
      if (sel) {
        atomicMin(&minselg[g], e);
        tp_part += mypull[k];
        maxsel_p = e > maxsel_p ? e : maxsel_p;
      }
    }
  }
  #pragma unroll
  for (int off = 32; off; off >>= 1) {
    int o = __shfl_xor(maxsel_p, off, 64);
    maxsel_p = o > maxsel_p ? o : maxsel_p;
  }
  if (lane == 0) atomicMax(&s_maxsel, maxsel_p);
  __syncthreads();

  // ---- pass 2: first-of-g subtraction; has_rem (only e > idx_last can have
  // idx_last as a killer, and all such e are killed) ----
  const int idx_last = s_maxsel;
  if (idx_last >= 0) {
    const int lw = idx_last >> 6;
    const unsigned long long lmask = ~(1ull << (idx_last & 63));
    #pragma unroll
    for (int k = 0; k < 4; ++k) {
      int e = tid + (k << 9);
      if (e < npos) {
        bool sel = (selw[e >> 6] >> (e & 63)) & 1ull;
        if (sel) {
          if (e == minselg[myag[k]]) tp_part -= mypull[k];  // first of its g
        } else if (e > idx_last) {
          // killed; active at i_last's turn iff only selected killer is i_last
          unsigned long long om = 0ull;
          const unsigned long long* row = rowp[k];
          const int We = myW[k];
          #pragma unroll
          for (int wp = 0; wp < 32; ++wp) {
            if (wp <= We) {
              unsigned long long m = row[wp] & selw[wp];
              if (wp == lw) m &= lmask;
              om |= m;
            }
          }
          if (om == 0ull) s_hasrem = 1;
        }
      }
    }
  }
  #pragma unroll
  for (int off = 32; off; off >>= 1) tp_part += __shfl_xor(tp_part, off, 64);
  if (lane == 0) wtp[wave] = tp_part;
  __syncthreads();

  // ---- push + finalize (wave 0; lane == g) ----
  if (wave == 0) {
    float mypush = 0.f;
    int mycnt2 = 0;
    int bp = bestposg[lane];
    bool seen = minselg[lane] < NN;
    if (bp < NN) {
      float h = gtb_all[b * GG * 4 + lane * 4 + 3] - gtb_all[b * GG * 4 + lane * 4 + 1];
      if (h >= MIN_H && !seen) { mypush = 1.0f - gtpiO[perm[bp]]; mycnt2 = 1; }
    }
    #pragma unroll
    for (int off = 32; off; off >>= 1) {
      mypush += __shfl_xor(mypush, off, 64);
      mycnt2 += __shfl_xor(mycnt2, off, 64);
    }
    if (lane == 0) {
      float tp = 0.f;
      #pragma unroll
      for (int w = 0; w < 8; ++w) tp += wtp[w];
      int total_sel = 0;
      for (int w = 0; w < 32; ++w) total_sel += __popcll(selw[w]);
      int distinct = 0;
      for (int g = 0; g < GG; ++g) distinct += (minselg[g] < NN) ? 1 : 0;
      int pc = total_sel - distinct;
      if (idx_last >= 0) {
        int ol = perm[idx_last];
        // last selection's pull counts only if non-first-of-g AND has_rem
        if (idx_last != minselg[agO[ol]] && !s_hasrem) tp -= pullO[ol];
      }
      float push_loss = 0.f, pull_loss = 0.f;
      if (npos > 1) {
        pull_loss = tp / ((float)pc + EPSF);
        push_loss = mypush / ((float)mycnt2 + EPSF);
      }
      atomicAdd(&out[0], push_loss * (1.0f / B_IMG));
      atomicAdd(&out[1], pull_loss * (1.0f / B_IMG));
    }
  }
}

extern "C" void kernel_launch(void* const* d_in, const int* in_sizes, int n_in,
                              void* d_out, int out_size, void* d_ws, size_t ws_size,
                              hipStream_t stream) {
  const int* agti = (const int*)d_in[1];
  const float* gtb = (const float*)d_in[2];
  const float* prop = (const float*)d_in[3];
  unsigned char* ws = (unsigned char*)d_ws;
  float* out = (float*)d_out;

  k_rank<<<B_IMG * 64, 256, 0, stream>>>(agti, gtb, prop, ws, out);
  k_pairs<<<B_IMG * NPAIRT * 4, 256, 0, stream>>>(ws);
  k_resolve<<<B_IMG, 512, 0, stream>>>(gtb, ws, out);
}

// Round 13
// 54.592 us; speedup vs baseline: 2.0222x; 1.0467x over previous
//
#include <hip/hip_runtime.h>
#include <math.h>

// NMSLoss4: B=8, N=2048, G=64. Key-sorted (desc) space: every killer of e has
// index < e, so an ordered blocked Gauss-Seidel sweep with distributed column
// folding gives the exact sequential-NMS fixed point. Round 12: depth-4
// column prefetch ring (covers remote-L2/HBM latency of atomicOr'd adj) and
// register-tracked selected-killer sets (kword/kmask/kmulti) so the has_rem
// pass needs no global reads — adj triangle is read exactly once.

#define B_IMG 8
#define NN 2048
#define GG 64
#define MIN_H 50.0f
#define EPSF 1e-6f
#define TILE 256
#define NTILE 8
#define NPAIRT 36            // triangular 256x256 tile pairs
#define CSLICE 64
#define ADJ_U64 33792        // sum over words W: 64*(W+1), W=0..31

// per-image ws layout (bytes) — all per-element arrays in ORIGINAL order
#define OFF_BOXO  0          // float4[2048]                 32768
#define OFF_GTPIO 32768      // f32[2048]                     8192
#define OFF_PULLO 40960      // f32[2048]                     8192
#define OFF_AGTIO 49152      // s8[2048]                      2048
#define OFF_NPOSP 51200      // u32[8] per-chunk counts (+pad)
#define OFF_RANKP 51456      // u16[8][2048]                 32768
#define OFF_ADJ   84224      // u64[33792] triangular (rank space) 270336
#define IMG_STRIDE 354560

__device__ __forceinline__ float iou_pair(
    float ax1, float ay1, float ax2, float ay2,
    float bx1, float by1, float bx2, float by2) {
  float area_a = (ax2 - ax1) * (ay2 - ay1);
  float area_b = (bx2 - bx1) * (by2 - by1);
  float lx = fmaxf(ax1, bx1), ly = fmaxf(ay1, by1);
  float rx = fminf(ax2, bx2), ry = fminf(ay2, by2);
  float w = fmaxf(rx - lx, 0.0f), h = fmaxf(ry - ly, 0.0f);
  float inter = w * h;
  return inter / (area_a + area_b - inter + 1e-10f);
}

__device__ __forceinline__ unsigned long long make_key(int a, float sc, int idx) {
  // higher key = earlier selection; ties -> lower orig idx (jnp.argmax).
  return (a >= 0)
      ? ((unsigned long long)__float_as_uint(sc) << 32) | (unsigned)(NN - 1 - idx)
      : 0ull;
}

// row base (u64 units) of rank-space element e in the triangular adj
__device__ __forceinline__ int adj_base(int e) {
  int W = e >> 6, l = e & 63;
  return 32 * W * (W + 1) + l * (W + 1);
}

// ------------- kernel 1: rank partials + per-elem prep + adj zero -----------
__global__ __launch_bounds__(256) void k_rank(
    const int* __restrict__ agti_all,
    const float* __restrict__ gtb_all,
    const float* __restrict__ prop_all,
    unsigned char* __restrict__ ws,
    float* __restrict__ out) {
  const int bidx = blockIdx.x;
  const int b = bidx >> 6;
  const int ec = (bidx >> 3) & 7, fc = bidx & 7;
  const int tid = threadIdx.x;
  const int* agti = agti_all + b * NN;
  const float* prop = prop_all + (size_t)b * NN * 5;
  unsigned char* W = ws + (size_t)b * IMG_STRIDE;

  if (bidx == 0 && tid == 0) { out[0] = 0.f; out[1] = 0.f; }

  // zero this image's adj (64 blocks per image cooperate)
  {
    unsigned long long* adj = (unsigned long long*)(W + OFF_ADJ);
    for (int t = ((bidx & 63) << 8) + tid; t < ADJ_U64; t += 64 * 256)
      adj[t] = 0ull;
  }

  __shared__ unsigned long long fkeys[TILE];
  __shared__ float sgt[GG * 4];
  __shared__ int cnt4[4];

  const int f0 = fc << 8;
  {
    const int f = f0 + tid;
    fkeys[tid] = make_key(agti[f], prop[f * 5 + 4], f);
  }
  if (fc == 0) sgt[tid] = gtb_all[b * GG * 4 + tid];

  const int e = (ec << 8) + tid;
  const int a = agti[e];
  const float sc = prop[e * 5 + 4];
  const unsigned long long myk = make_key(a, sc, e);
  const bool pos = a >= 0;
  {
    unsigned long long bal = __ballot(pos);
    if ((tid & 63) == 0) cnt4[tid >> 6] = __popcll(bal);
  }
  __syncthreads();

  int rank = 0;
  #pragma unroll 16
  for (int ff = 0; ff < TILE; ++ff) {
    unsigned long long kf = fkeys[ff];       // LDS broadcast
    int fi = f0 + ff;
    rank += (kf > myk || (kf == myk && fi < e)) ? 1 : 0;
  }
  ((unsigned short*)(W + OFF_RANKP))[(fc << 11) + e] = (unsigned short)rank;

  if (fc == 0) {
    // per-element prep in ORIGINAL order + chunk positive count
    float4 bx = make_float4(prop[e * 5 + 0], prop[e * 5 + 1],
                            prop[e * 5 + 2], prop[e * 5 + 3]);
    float gi = 0.f, pl = 0.f;
    if (pos) {
      gi = iou_pair(sgt[a * 4 + 0], sgt[a * 4 + 1], sgt[a * 4 + 2], sgt[a * 4 + 3],
                    bx.x, bx.y, bx.z, bx.w);
      pl = -logf(fminf(0.5f + fmaxf(gi, EPSF), 1.0f)) * sc;
    }
    ((float4*)(W + OFF_BOXO))[e] = bx;
    ((float*)(W + OFF_GTPIO))[e] = gi;
    ((float*)(W + OFF_PULLO))[e] = pl;
    ((signed char*)(W + OFF_AGTIO))[e] = (signed char)a;
    if (tid == 0)
      ((unsigned*)(W + OFF_NPOSP))[ec] =
          (unsigned)(cnt4[0] + cnt4[1] + cnt4[2] + cnt4[3]);
  }
}

__device__ __forceinline__ int load_npos(const unsigned char* W) {
  const unsigned* np = (const unsigned*)(W + OFF_NPOSP);
  return (int)(np[0] + np[1] + np[2] + np[3] + np[4] + np[5] + np[6] + np[7]);
}

// ------------- kernel 2: tiled all-pairs (orig space) -> adj @ rank coords --
// Exact divide-free predicate:
// fl32(inter/denom) > 0.5f  <=>  (double)inter > (0.5+2^-25)*(double)denom
// Edge direction by rank: killer = smaller rank. Negatives rank >= npos, so
// they can only be victims (rows never read by the sweep) — no pos check.
__global__ __launch_bounds__(256) void k_pairs(unsigned char* __restrict__ ws) {
  int bx = blockIdx.x;
  const int b = bx / (NPAIRT * 4);
  int rem = bx % (NPAIRT * 4);
  int p = rem >> 2;
  const int q = rem & 3;
  int r = 0;
  #pragma unroll
  for (int t = 0; t < NTILE; ++t) {
    int wdt = NTILE - t;
    if (p < wdt) { r = t; break; }
    p -= wdt;
  }
  const int c = r + p;
  const int tid = threadIdx.x;
  unsigned char* W = ws + (size_t)b * IMG_STRIDE;
  const float4* box = (const float4*)(W + OFF_BOXO);
  const unsigned short* rp = (const unsigned short*)(W + OFF_RANKP);
  unsigned long long* adj = (unsigned long long*)(W + OFF_ADJ);

  __shared__ float4 cbox[CSLICE];
  __shared__ float carea[CSLICE];
  __shared__ unsigned short crank[CSLICE];

  const int jbase = c * TILE + q * CSLICE;
  if (tid < CSLICE) {
    int j = jbase + tid;
    float4 Bx = box[j];
    cbox[tid] = Bx;
    carea[tid] = (Bx.z - Bx.x) * (Bx.w - Bx.y);
    int rj = 0;
    #pragma unroll
    for (int fc = 0; fc < 8; ++fc) rj += rp[(fc << 11) + j];
    crank[tid] = (unsigned short)rj;
  }
  const int i = r * TILE + tid;
  const float4 A = box[i];
  const float area_a = (A.z - A.x) * (A.w - A.y);
  int ri = 0;
  #pragma unroll
  for (int fc = 0; fc < 8; ++fc) ri += rp[(fc << 11) + i];
  __syncthreads();

  const double THR = 0.5 + 0x1p-25;
  #pragma unroll 8
  for (int jj = 0; jj < CSLICE; ++jj) {
    float4 Bx = cbox[jj];
    float ab = carea[jj];
    float lx = fmaxf(A.x, Bx.x), ly = fmaxf(A.y, Bx.y);
    float rx = fminf(A.z, Bx.z), ry = fminf(A.w, Bx.w);
    float w = fmaxf(rx - lx, 0.0f), h = fmaxf(ry - ly, 0.0f);
    float inter = w * h;
    float denom = area_a + ab - inter + 1e-10f;   // ((aa+ab)-inter)+eps
    int j = jbase + jj;
    bool hit = ((double)inter > THR * (double)denom) && (j > i);
    if (hit) {
      int rj = crank[jj];
      int rv = ri > rj ? ri : rj;     // victim = larger rank
      int rk = ri > rj ? rj : ri;     // killer = smaller rank
      atomicOr(&adj[adj_base(rv) + (rk >> 6)], 1ull << (rk & 63));
    }
  }
}

// ------------- kernel 3: perm build + distributed sweep + bookkeeping -------
__global__ __launch_bounds__(512) void k_resolve(
    const float* __restrict__ gtb_all,
    unsigned char* __restrict__ ws,
    float* __restrict__ out) {
  const int b = blockIdx.x, tid = threadIdx.x;
  const int wave = tid >> 6, lane = tid & 63;
  unsigned char* W = ws + (size_t)b * IMG_STRIDE;
  const float* gtpiO = (const float*)(W + OFF_GTPIO);
  const float* pullO = (const float*)(W + OFF_PULLO);
  const signed char* agO = (const signed char*)(W + OFF_AGTIO);
  const unsigned long long* adj = (const unsigned long long*)(W + OFF_ADJ);
  const int npos = load_npos(W);

  __shared__ unsigned short perm[NN];          // sorted(rank) -> orig
  __shared__ unsigned long long selw[32];
  __shared__ int minselg[GG], bestposg[GG];
  __shared__ int s_maxsel, s_hasrem;
  __shared__ float wtp[8];

  // thread owns sorted elements e = tid + k*512, word myW[k] = k*8 + wave.
  // word w committed by wave (w&7), slot k = w>>3. Columns prefetched 4-deep
  // in a register ring cb[k][w&3] (all indices compile-time).
  const unsigned long long* rowp[4];
  unsigned long long diag[4], cb[4][4], kmask[4];
  int myW[4], kword[4];
  bool kmulti[4];
  #pragma unroll
  for (int k = 0; k < 4; ++k) {
    const int e = tid + (k << 9);
    myW[k] = (k << 3) + wave;
    rowp[k] = adj + adj_base(e);
    diag[k] = rowp[k][myW[k]];                    // intra-word killer mask
    #pragma unroll
    for (int j = 0; j < 4; ++j)
      cb[k][j] = (myW[k] > j) ? rowp[k][j] : 0ull;
    kword[k] = -1; kmask[k] = 0ull; kmulti[k] = false;
  }

  // perm: orig -> rank from partials, scatter into LDS
  {
    const unsigned short* rp = (const unsigned short*)(W + OFF_RANKP);
    #pragma unroll
    for (int k = 0; k < 4; ++k) {
      int o = tid + (k << 9);                    // original index
      int rank = 0;
      #pragma unroll
      for (int fc = 0; fc < 8; ++fc) rank += rp[(fc << 11) + o];
      perm[rank] = (unsigned short)o;
    }
  }
  if (tid == 0) { s_maxsel = -1; s_hasrem = 0; }
  if (tid < GG) { minselg[tid] = NN; bestposg[tid] = NN; }
  __syncthreads();

  // gather per-owned-sorted-element data through perm
  float mypull[4];
  int myag[4];
  #pragma unroll
  for (int k = 0; k < 4; ++k) {
    int e = tid + (k << 9);
    int o = perm[e];
    mypull[k] = pullO[o];
    myag[k] = agO[o];
  }

  // ---- blocked Gauss-Seidel sweep: one barrier per word step ----
  #pragma unroll
  for (int w = 0; w < 32; ++w) {
    if (wave == (w & 7)) {
      const int k = w >> 3;                      // compile-time
      const int e = (w << 6) | lane;
      const bool alive0 = (e < npos) && (kword[k] < 0);
      const unsigned long long intra = diag[k];  // only bits < lane set
      bool alive = alive0;
      unsigned long long bal = __ballot(alive), prev;
      do {
        prev = bal;
        alive = alive0 && ((intra & bal) == 0ull);
        bal = __ballot(alive);
      } while (bal != prev);
      if (lane == 0) selw[w] = bal;
      // record intra-word SELECTED killers for has_rem bookkeeping
      unsigned long long mi = intra & bal;
      if (mi != 0ull) {
        kmulti[k] = kmulti[k] || (kword[k] >= 0);
        if (kword[k] < 0) { kword[k] = w; kmask[k] = mi; }
      }
    }
    __syncthreads();                             // selw[w] visible to all
    const unsigned long long sw = selw[w];
    #pragma unroll
    for (int k = 0; k < 4; ++k) {
      if (myW[k] > w) {
        unsigned long long m = cb[k][w & 3] & sw; // fold column w
        if (m != 0ull) {
          kmulti[k] = kmulti[k] || (kword[k] >= 0);
          if (kword[k] < 0) { kword[k] = w; kmask[k] = m; }
        }
      }
      cb[k][w & 3] = (myW[k] > w + 4) ? rowp[k][w + 4] : 0ull;  // prefetch w+4
    }
  }
  __syncthreads();

  // ---- bookkeeping pass 1 ----
  float tp_part = 0.f;
  int maxsel_p = -1;
  #pragma unroll
  for (int k = 0; k < 4; ++k) {
    int e = tid + (k << 9);
    if (e < npos) {
      int g = myag[k];                           // e<npos => positive
      atomicMin(&bestposg[g], e);
      bool sel = (selw[e >> 6] >> (e & 63)) & 1ull;
      if (sel) {
        atomicMin(&minselg[g], e);
        tp_part += mypull[k];
        maxsel_p = e > maxsel_p ? e : maxsel_p;
      }
    }
  }
  #pragma unroll
  for (int off = 32; off; off >>= 1) {
    int o = __shfl_xor(maxsel_p, off, 64);
    maxsel_p = o > maxsel_p ? o : maxsel_p;
  }
  if (lane == 0) atomicMax(&s_maxsel, maxsel_p);
  __syncthreads();

  // ---- pass 2: first-of-g subtraction; has_rem from REGISTERS ----
  // killed e is active at idx_last's turn iff its selected-killer set is
  // exactly {idx_last}: single word (lw), single bit (lbit). Killer rank <
  // victim rank makes e > idx_last automatic.
  const int idx_last = s_maxsel;
  if (idx_last >= 0) {
    const int lw = idx_last >> 6;
    const unsigned long long lbit = 1ull << (idx_last & 63);
    #pragma unroll
    for (int k = 0; k < 4; ++k) {
      int e = tid + (k << 9);
      if (e < npos) {
        bool sel = (selw[e >> 6] >> (e & 63)) & 1ull;
        if (sel) {
          if (e == minselg[myag[k]]) tp_part -= mypull[k];  // first of its g
        } else if (!kmulti[k] && kword[k] == lw && kmask[k] == lbit) {
          s_hasrem = 1;
        }
      }
    }
  }
  #pragma unroll
  for (int off = 32; off; off >>= 1) tp_part += __shfl_xor(tp_part, off, 64);
  if (lane == 0) wtp[wave] = tp_part;
  __syncthreads();

  // ---- push + finalize (wave 0; lane == g) ----
  if (wave == 0) {
    float mypush = 0.f;
    int mycnt2 = 0;
    int bp = bestposg[lane];
    bool seen = minselg[lane] < NN;
    if (bp < NN) {
      float h = gtb_all[b * GG * 4 + lane * 4 + 3] - gtb_all[b * GG * 4 + lane * 4 + 1];
      if (h >= MIN_H && !seen) { mypush = 1.0f - gtpiO[perm[bp]]; mycnt2 = 1; }
    }
    #pragma unroll
    for (int off = 32; off; off >>= 1) {
      mypush += __shfl_xor(mypush, off, 64);
      mycnt2 += __shfl_xor(mycnt2, off, 64);
    }
    if (lane == 0) {
      float tp = 0.f;
      #pragma unroll
      for (int w = 0; w < 8; ++w) tp += wtp[w];
      int total_sel = 0;
      for (int w = 0; w < 32; ++w) total_sel += __popcll(selw[w]);
      int distinct = 0;
      for (int g = 0; g < GG; ++g) distinct += (minselg[g] < NN) ? 1 : 0;
      int pc = total_sel - distinct;
      if (idx_last >= 0) {
        int ol = perm[idx_last];
        // last selection's pull counts only if non-first-of-g AND has_rem
        if (idx_last != minselg[agO[ol]] && !s_hasrem) tp -= pullO[ol];
      }
      float push_loss = 0.f, pull_loss = 0.f;
      if (npos > 1) {
        pull_loss = tp / ((float)pc + EPSF);
        push_loss = mypush / ((float)mycnt2 + EPSF);
      }
      atomicAdd(&out[0], push_loss * (1.0f / B_IMG));
      atomicAdd(&out[1], pull_loss * (1.0f / B_IMG));
    }
  }
}

extern "C" void kernel_launch(void* const* d_in, const int* in_sizes, int n_in,
                              void* d_out, int out_size, void* d_ws, size_t ws_size,
                              hipStream_t stream) {
  const int* agti = (const int*)d_in[1];
  const float* gtb = (const float*)d_in[2];
  const float* prop = (const float*)d_in[3];
  unsigned char* ws = (unsigned char*)d_ws;
  float* out = (float*)d_out;

  k_rank<<<B_IMG * 64, 256, 0, stream>>>(agti, gtb, prop, ws, out);
  k_pairs<<<B_IMG * NPAIRT * 4, 256, 0, stream>>>(ws);
  k_resolve<<<B_IMG, 512, 0, stream>>>(gtb, ws, out);
}